// Round 12
// baseline (325.247 us; speedup 1.0000x reference)
//
#include <hip/hip_runtime.h>
#include <hip/hip_bf16.h>

#define NN 2048

typedef __attribute__((ext_vector_type(4))) float f32x4;
typedef __attribute__((ext_vector_type(8))) short bf16x8;

__device__ __forceinline__ unsigned short f2bf(float f) {
  __hip_bfloat16 h = __float2bfloat16(f);
  return __builtin_bit_cast(unsigned short, h);
}
__device__ __forceinline__ unsigned int pk2(float a, float b) {
  return (unsigned int)f2bf(a) | ((unsigned int)f2bf(b) << 16);
}
__device__ __forceinline__ void gld_lds16(const void* g, void* l) {
  __builtin_amdgcn_global_load_lds(
      (const __attribute__((address_space(1))) unsigned int*)g,
      (__attribute__((address_space(3))) unsigned int*)l, 16, 0, 0);
}

// Merged transpose+cvt: f32 (R x C) -> bf16 (C x R) for X (batched), W1, W2.
__global__ void k_tr_all(const float* __restrict__ X, unsigned short* __restrict__ XT,
                         const float* __restrict__ W1, unsigned short* __restrict__ W1T,
                         const float* __restrict__ W2, unsigned short* __restrict__ W2T) {
  int bid = blockIdx.x;
  const float* src;
  unsigned short* dst;
  int R, C, bx, by, b;
  if (bid < 8192) {  // X: per batch 64 x 4 tiles, 32 batches
    src = X; dst = XT; R = 2048; C = 128;
    b = bid >> 8;
    int r = bid & 255;
    bx = r & 63; by = r >> 6;
  } else if (bid < 8192 + 32) {  // W1: 128 x 256 -> 4 x 8 tiles
    src = W1; dst = W1T; R = 128; C = 256; b = 0;
    int r = bid - 8192;
    bx = r & 3; by = r >> 2;
  } else {  // W2: 256 x 256 -> 8 x 8 tiles
    src = W2; dst = W2T; R = 256; C = 256; b = 0;
    int r = bid - 8224;
    bx = r & 7; by = r >> 3;
  }
  src += (size_t)b * R * C;
  dst += (size_t)b * R * C;
  __shared__ float tile[32][33];
  int r0 = bx * 32, c0 = by * 32;
  int t = threadIdx.x;
  int r = t >> 3, c4 = (t & 7) << 2;
  float4 v = *(const float4*)(src + (size_t)(r0 + r) * C + c0 + c4);
  tile[r][c4 + 0] = v.x; tile[r][c4 + 1] = v.y; tile[r][c4 + 2] = v.z; tile[r][c4 + 3] = v.w;
  __syncthreads();
  ushort4 o;
  o.x = f2bf(tile[c4 + 0][r]); o.y = f2bf(tile[c4 + 1][r]);
  o.z = f2bf(tile[c4 + 2][r]); o.w = f2bf(tile[c4 + 3][r]);
  *(ushort4*)(dst + (size_t)(c0 + r) * R + r0 + c4) = o;
}

// ---------------- Layer-1 fused kernel (R7-proven, unchanged) ----------------
#define AGG_STEP(KT, AREGC, AREGN, CUR, VMC)                                   \
  {                                                                            \
    const int kt_ = (KT);                                                      \
    if (kt_ < NKT - 1) { /* B tile kt+1 -> Bs[nxt]; issued first (oldest) */   \
      _Pragma("unroll") for (int i = 0; i < NF; ++i) {                         \
        int jj = i * 512 + t;                                                  \
        int n_ = jj >> 3, s_ = jj & 7, sp_ = s_ ^ (n_ & 7);                    \
        gld_lds16(BTb + (size_t)n_ * NN + (size_t)(kt_ + 1) * 64 + sp_ * 8,    \
                  &Bs[(CUR) ^ 1][(i * 512 + wid * 64) * 8]);                   \
      }                                                                        \
    }                                                                          \
    __builtin_amdgcn_sched_barrier(0); /* pin: B ops issue before A ops */     \
    if (kt_ < NKT - 2) { /* A loads for kt+2; stay in flight over barrier */   \
      const float* p_ = apb + (size_t)(kt_ + 2) * 64;                          \
      _Pragma("unroll") for (int j = 0; j < 4; ++j)                            \
          AREGN[j] = ((const float4*)p_)[j];                                   \
    }                                                                          \
    if (kt_ < NKT - 1) { /* cvt A(kt+1) regs (landed long ago) -> As[nxt] */   \
      _Pragma("unroll") for (int i = 0; i < 2; ++i) {                          \
        uint4 w_;                                                              \
        w_.x = pk2(AREGC[2 * i].x, AREGC[2 * i].y);                            \
        w_.y = pk2(AREGC[2 * i].z, AREGC[2 * i].w);                            \
        w_.z = pk2(AREGC[2 * i + 1].x, AREGC[2 * i + 1].y);                    \
        w_.w = pk2(AREGC[2 * i + 1].z, AREGC[2 * i + 1].w);                    \
        int s_ = ak * 2 + i, sp_ = s_ ^ (ar & 7);                              \
        *(uint4*)&As[(CUR) ^ 1][(ar * 8 + sp_) * 8] = w_;                      \
      }                                                                        \
    }                                                                          \
    _Pragma("unroll") for (int kh = 0; kh < 2; ++kh) {                         \
      bf16x8 af[4], bfr[NF];                                                   \
      _Pragma("unroll") for (int mi = 0; mi < 4; ++mi) {                       \
        int row = wr * 64 + mi * 16 + lr;                                      \
        int sp_ = (kh * 4 + q) ^ (row & 7);                                    \
        af[mi] = *(const bf16x8*)&As[CUR][(row * 8 + sp_) * 8];                \
      }                                                                        \
      _Pragma("unroll") for (int ni = 0; ni < NF; ++ni) {                      \
        int brow = wc * WN + ni * 16 + lr;                                     \
        int sp_ = (kh * 4 + q) ^ (brow & 7);                                   \
        bfr[ni] = *(const bf16x8*)&Bs[CUR][(brow * 8 + sp_) * 8];              \
      }                                                                        \
      _Pragma("unroll") for (int mi = 0; mi < 4; ++mi)                         \
        _Pragma("unroll") for (int ni = 0; ni < NF; ++ni)                      \
          acc[mi][ni] = __builtin_amdgcn_mfma_f32_16x16x32_bf16(               \
              af[mi], bfr[ni], acc[mi][ni], 0, 0, 0);                          \
    }                                                                          \
    asm volatile("s_waitcnt vmcnt(" #VMC ") lgkmcnt(0)" ::: "memory");         \
    __builtin_amdgcn_s_barrier();                                              \
  }

template <int NCOLS, int MODE>
__global__ __launch_bounds__(512, NCOLS == 128 ? 4 : 2) void k_agg_fused(
    const float* __restrict__ A, const unsigned short* __restrict__ BT,
    const unsigned short* __restrict__ WT, const float* __restrict__ bias,
    const float* __restrict__ gamma, const float* __restrict__ beta,
    unsigned short* __restrict__ HTout, float* __restrict__ gpart) {
  constexpr int WN = NCOLS / 4;
  constexpr int NF = NCOLS / 64;
  constexpr int NKT = NN / 64;
  constexpr int FIN = NCOLS;
  constexpr int NQT = FIN / 64;
  constexpr int NMB = NN / 128;

  __shared__ __align__(16) unsigned short As[2][128 * 64];
  __shared__ __align__(16) unsigned short Bs[2][NCOLS * 64];
  __shared__ float red[2][128][4];

  int L = blockIdx.x + gridDim.x * blockIdx.z;
  int xcd = L & 7, slot = L >> 3;
  int mb = slot % NMB;
  int b = xcd + 8 * (slot / NMB);
  int m0 = mb * 128;

  const float* Ab = A + (size_t)b * NN * NN;
  const unsigned short* BTb = BT + (size_t)b * (size_t)NCOLS * NN;
  int t = threadIdx.x, lane = t & 63, wid = t >> 6;
  int wr = wid >> 2, wc = wid & 3;
  int q = lane >> 4, lr = lane & 15;
  int ar = t >> 2, ak = t & 3;
  const float* apb = Ab + (size_t)(m0 + ar) * NN + ak * 16;

  f32x4 acc[4][NF] = {};
  float4 aregA[4], aregB[4];

  {
#pragma unroll
    for (int j = 0; j < 4; ++j) aregA[j] = ((const float4*)apb)[j];
#pragma unroll
    for (int i = 0; i < NF; ++i) {
      int jj = i * 512 + t;
      int n = jj >> 3, s = jj & 7, sp = s ^ (n & 7);
      gld_lds16(BTb + (size_t)n * NN + sp * 8, &Bs[0][(i * 512 + wid * 64) * 8]);
    }
#pragma unroll
    for (int i = 0; i < 2; ++i) {
      uint4 w;
      w.x = pk2(aregA[2 * i].x, aregA[2 * i].y);
      w.y = pk2(aregA[2 * i].z, aregA[2 * i].w);
      w.z = pk2(aregA[2 * i + 1].x, aregA[2 * i + 1].y);
      w.w = pk2(aregA[2 * i + 1].z, aregA[2 * i + 1].w);
      int s = ak * 2 + i, sp = s ^ (ar & 7);
      *(uint4*)&As[0][(ar * 8 + sp) * 8] = w;
    }
    __builtin_amdgcn_sched_barrier(0);
#pragma unroll
    for (int j = 0; j < 4; ++j) aregB[j] = ((const float4*)(apb + 64))[j];
    asm volatile("s_waitcnt vmcnt(4) lgkmcnt(0)" ::: "memory");
    __builtin_amdgcn_s_barrier();
  }

  for (int k2 = 0; k2 < NKT / 2 - 1; ++k2) {
    AGG_STEP(2 * k2, aregB, aregA, 0, 4);
    AGG_STEP(2 * k2 + 1, aregA, aregB, 1, 4);
  }
  AGG_STEP(NKT - 2, aregB, aregA, 0, 0);
  AGG_STEP(NKT - 1, aregA, aregB, 1, 0);

  unsigned short* Hs = (NCOLS == 128) ? &As[0][0] : &Bs[0][0];
  unsigned short* Ws = (NCOLS == 128) ? &Bs[0][0] : &As[0][0];
#pragma unroll
  for (int mi = 0; mi < 4; ++mi) {
#pragma unroll
    for (int ni = 0; ni < NF; ++ni) {
#pragma unroll
      for (int j = 0; j < 4; ++j) {
        int row = wr * 64 + mi * 16 + q * 4 + j;
        int col = wc * WN + ni * 16 + lr;
        int sp = (col >> 3) ^ (row & 7);
        Hs[row * FIN + sp * 8 + (col & 7)] = f2bf(acc[mi][ni][j]);
      }
    }
  }

  f32x4 acc2[4][4] = {};
  for (int qt = 0; qt < NQT; ++qt) {
    __syncthreads();
#pragma unroll
    for (int i = 0; i < 4; ++i) {
      int jj = i * 512 + t;
      int h = jj >> 3, s = jj & 7, sp = s ^ (h & 7);
      gld_lds16(WT + (size_t)h * FIN + qt * 64 + sp * 8, Ws + (i * 512 + wid * 64) * 8);
    }
    __syncthreads();
#pragma unroll
    for (int kh = 0; kh < 2; ++kh) {
      bf16x8 hf[4], wf[4];
#pragma unroll
      for (int mi = 0; mi < 4; ++mi) {
        int row = wr * 64 + mi * 16 + lr;
        int slotk = qt * 8 + kh * 4 + q;
        int sp = slotk ^ (row & 7);
        hf[mi] = *(const bf16x8*)&Hs[row * FIN + sp * 8];
      }
#pragma unroll
      for (int ni = 0; ni < 4; ++ni) {
        int h = wc * 64 + ni * 16 + lr;
        int sp = (kh * 4 + q) ^ (h & 7);
        wf[ni] = *(const bf16x8*)&Ws[(h * 8 + sp) * 8];
      }
#pragma unroll
      for (int mi = 0; mi < 4; ++mi) {
#pragma unroll
        for (int ni = 0; ni < 4; ++ni)
          acc2[mi][ni] = __builtin_amdgcn_mfma_f32_16x16x32_bf16(hf[mi], wf[ni], acc2[mi][ni], 0, 0, 0);
      }
    }
  }

  float bcol[4], gcol[4], zcol[4];
#pragma unroll
  for (int ni = 0; ni < 4; ++ni) {
    int col = wc * 64 + ni * 16 + lr;
    bcol[ni] = bias[col]; gcol[ni] = gamma[col]; zcol[ni] = beta[col];
  }
#pragma unroll
  for (int mi = 0; mi < 4; ++mi) {
#pragma unroll
    for (int j = 0; j < 4; ++j) {
      float s = 0.f, ss = 0.f;
#pragma unroll
      for (int ni = 0; ni < 4; ++ni) {
        float v = acc2[mi][ni][j] + bcol[ni];
        acc2[mi][ni][j] = v;
        s += v; ss += v * v;
      }
#pragma unroll
      for (int m = 1; m < 16; m <<= 1) { s += __shfl_xor(s, m); ss += __shfl_xor(ss, m); }
      if (lr == 0) {
        int rl = wr * 64 + mi * 16 + q * 4 + j;
        red[0][rl][wc] = s;
        red[1][rl][wc] = ss;
      }
    }
  }
  __syncthreads();
#pragma unroll
  for (int mi = 0; mi < 4; ++mi) {
#pragma unroll
    for (int j = 0; j < 4; ++j) {
      int rl = wr * 64 + mi * 16 + q * 4 + j;
      float s = red[0][rl][0] + red[0][rl][1] + red[0][rl][2] + red[0][rl][3];
      float ss = red[1][rl][0] + red[1][rl][1] + red[1][rl][2] + red[1][rl][3];
      float mean = s * (1.f / 256.f);
      float var = ss * (1.f / 256.f) - mean * mean;
      float inv = rsqrtf(var + 1e-5f);
#pragma unroll
      for (int ni = 0; ni < 4; ++ni) {
        float v = (acc2[mi][ni][j] - mean) * inv * gcol[ni] + zcol[ni];
        acc2[mi][ni][j] = v > 0.f ? v : 0.f;
      }
    }
  }
  if (MODE == 0) {
#pragma unroll
    for (int mi = 0; mi < 4; ++mi) {
#pragma unroll
      for (int ni = 0; ni < 4; ++ni) {
        int col = wc * 64 + ni * 16 + lr;
        int rowb = m0 + wr * 64 + mi * 16 + q * 4;
        ushort4 o;
        o.x = f2bf(acc2[mi][ni][0]); o.y = f2bf(acc2[mi][ni][1]);
        o.z = f2bf(acc2[mi][ni][2]); o.w = f2bf(acc2[mi][ni][3]);
        *(ushort4*)(HTout + ((size_t)b * 256 + col) * NN + rowb) = o;
      }
    }
  } else {
#pragma unroll
    for (int ni = 0; ni < 4; ++ni) {
      float cs = 0.f;
#pragma unroll
      for (int mi = 0; mi < 4; ++mi) {
#pragma unroll
        for (int j = 0; j < 4; ++j) cs += acc2[mi][ni][j];
      }
      cs += __shfl_xor(cs, 16);
      cs += __shfl_xor(cs, 32);
      if (q == 0) {
        int col = wc * 64 + ni * 16 + lr;
        gpart[(((size_t)b * NMB + mb) * 2 + wr) * 256 + col] = cs;
      }
    }
  }
}

// ---- Layer-2: A in REGISTERS (per-wave, no LDS, no barrier coupling) ----
// Wave w owns output rows w*16..w*16+15 x all 256 cols (acc = 16 x f32x4).
// Per lane: A[m0+w*16+(lane&15)][k=(lane>>4)*8+..] loaded straight from
// global (4 float4/step), cvt f32->bf16 in-register, fed to MFMA as the
// first operand. Only B goes through LDS (double-buffered, 1 barrier/step,
// counted vmcnt). LDS = 64 KB Bs + 16 KB Ws/red = 80 KB -> 2 blocks/CU.
__global__ __launch_bounds__(512, 4) void k_agg2(
    const float* __restrict__ A, const unsigned short* __restrict__ BT,
    const unsigned short* __restrict__ WT, const float* __restrict__ bias,
    const float* __restrict__ gamma, const float* __restrict__ beta,
    float* __restrict__ gpart) {
  constexpr int NMB = 16;

  __shared__ __align__(16) unsigned short Bs[2][256 * 64];  // 64 KB
  __shared__ __align__(16) char wsregion[16 * 1024];        // Ws eighth / red
  unsigned short* Ws = (unsigned short*)wsregion;
  float* redp = (float*)wsregion;

  int L = blockIdx.x + gridDim.x * blockIdx.z;
  int xcd = L & 7, slot = L >> 3;
  int mb = slot % NMB;
  int b = xcd + 8 * (slot / NMB);
  int m0 = mb * 128;

  const float* Ab = A + (size_t)b * NN * NN;
  const unsigned short* BTb = BT + (size_t)b * (size_t)256 * NN;
  int t = threadIdx.x, lane = t & 63, wid = t >> 6;
  int q = lane >> 4, lr = lane & 15;
  // per-lane A base: row = m0 + wid*16 + lr, k-lane-offset = q*8
  const float* apl = Ab + (size_t)(m0 + wid * 16 + lr) * NN + q * 8;

  f32x4 acc[16] = {};
  float4 areg[4];

  // prologue: A(0)->regs, B(0)->Bs[0], full drain, barrier.
  {
    areg[0] = *(const float4*)(apl);
    areg[1] = *(const float4*)(apl + 4);
    areg[2] = *(const float4*)(apl + 32);
    areg[3] = *(const float4*)(apl + 36);
#pragma unroll
    for (int i = 0; i < 4; ++i) {
      int jj = i * 512 + t;
      int n = jj >> 3, s = jj & 7, sp = s ^ (n & 7);
      gld_lds16(BTb + (size_t)n * NN + sp * 8, &Bs[0][(i * 512 + wid * 64) * 8]);
    }
    asm volatile("s_waitcnt vmcnt(0) lgkmcnt(0)" ::: "memory");
    __builtin_amdgcn_s_barrier();
  }

  for (int kt = 0; kt < 32; ++kt) {
    const unsigned short* bcu = &Bs[kt & 1][0];
    unsigned short* bnx = &Bs[(kt & 1) ^ 1][0];
    if (kt < 31) {  // stage B(kt+1) (oldest vmem ops of this step)
#pragma unroll
      for (int i = 0; i < 4; ++i) {
        int jj = i * 512 + t;
        int n = jj >> 3, s = jj & 7, sp = s ^ (n & 7);
        gld_lds16(BTb + (size_t)n * NN + (size_t)(kt + 1) * 64 + sp * 8,
                  bnx + (i * 512 + wid * 64) * 8);
      }
    }
    __builtin_amdgcn_sched_barrier(0);
    // cvt A(kt) regs -> bf16 fragments (frees areg)
    bf16x8 af0, af1;
    {
      uint4 u0, u1;
      u0.x = pk2(areg[0].x, areg[0].y); u0.y = pk2(areg[0].z, areg[0].w);
      u0.z = pk2(areg[1].x, areg[1].y); u0.w = pk2(areg[1].z, areg[1].w);
      u1.x = pk2(areg[2].x, areg[2].y); u1.y = pk2(areg[2].z, areg[2].w);
      u1.z = pk2(areg[3].x, areg[3].y); u1.w = pk2(areg[3].z, areg[3].w);
      af0 = __builtin_bit_cast(bf16x8, u0);
      af1 = __builtin_bit_cast(bf16x8, u1);
    }
    if (kt < 31) {  // issue A(kt+1); lands during this step's barrier wait
      const float* p = apl + (size_t)(kt + 1) * 64;
      areg[0] = *(const float4*)(p);
      areg[1] = *(const float4*)(p + 4);
      areg[2] = *(const float4*)(p + 32);
      areg[3] = *(const float4*)(p + 36);
    }
#pragma unroll
    for (int kh = 0; kh < 2; ++kh) {
      bf16x8 afk = kh ? af1 : af0;
#pragma unroll
      for (int ni = 0; ni < 16; ++ni) {
        int brow = ni * 16 + lr;
        int sp = (kh * 4 + q) ^ (brow & 7);
        bf16x8 bfr = *(const bf16x8*)(bcu + (brow * 8 + sp) * 8);
        acc[ni] = __builtin_amdgcn_mfma_f32_16x16x32_bf16(afk, bfr, acc[ni], 0, 0, 0);
      }
    }
    if (kt < 31) {
      asm volatile("s_waitcnt vmcnt(4) lgkmcnt(0)" ::: "memory");  // A(kt+1) flies
    } else {
      asm volatile("s_waitcnt vmcnt(0) lgkmcnt(0)" ::: "memory");
    }
    __builtin_amdgcn_s_barrier();
  }

  // ---- epilogue: acc -> Hs (bf16, swizzled) in Bs region (64 KB) ----
  unsigned short* Hs = &Bs[0][0];
#pragma unroll
  for (int ni = 0; ni < 16; ++ni) {
#pragma unroll
    for (int j = 0; j < 4; ++j) {
      int row = wid * 16 + q * 4 + j;
      int col = ni * 16 + lr;
      int sp = (col >> 3) ^ (row & 7);
      Hs[row * 256 + sp * 8 + (col & 7)] = f2bf(acc[ni][j]);
    }
  }

  // ---- linear: acc2 = Hs @ W2, W^T staged in EIGHTHS (256x32 = 16 KB) ----
  int wr = wid >> 2, wc = wid & 3;
  f32x4 acc2[4][4] = {};
  for (int qt = 0; qt < 8; ++qt) {
    // prev eighth's Ws reads done (qt=0: Hs ds_writes done)
    asm volatile("s_waitcnt lgkmcnt(0)" ::: "memory");
    __builtin_amdgcn_s_barrier();
#pragma unroll
    for (int i = 0; i < 2; ++i) {
      int jj = i * 512 + t;
      int h = jj >> 2, spp = jj & 3, spl = spp ^ (h & 3);
      gld_lds16(WT + (size_t)h * 256 + qt * 32 + spl * 8,
                Ws + (i * 512 + wid * 64) * 8);
    }
    asm volatile("s_waitcnt vmcnt(0) lgkmcnt(0)" ::: "memory");
    __builtin_amdgcn_s_barrier();
    bf16x8 hf[4], wf[4];
#pragma unroll
    for (int mi = 0; mi < 4; ++mi) {
      int row = wr * 64 + mi * 16 + lr;
      int slotk = qt * 4 + q;
      int sp = slotk ^ (row & 7);
      hf[mi] = *(const bf16x8*)&Hs[row * 256 + sp * 8];
    }
#pragma unroll
    for (int ni = 0; ni < 4; ++ni) {
      int h = wc * 64 + ni * 16 + lr;
      int sp = q ^ (h & 3);
      wf[ni] = *(const bf16x8*)&Ws[(h * 4 + sp) * 8];
    }
#pragma unroll
    for (int mi = 0; mi < 4; ++mi)
#pragma unroll
      for (int ni = 0; ni < 4; ++ni)
        acc2[mi][ni] = __builtin_amdgcn_mfma_f32_16x16x32_bf16(hf[mi], wf[ni], acc2[mi][ni], 0, 0, 0);
  }
  asm volatile("s_waitcnt lgkmcnt(0)" ::: "memory");
  __builtin_amdgcn_s_barrier();  // Ws reads done before redp overlay goes live

  // ---- bias + LayerNorm(256) + relu + column partials ----
  float bcol[4], gcol[4], zcol[4];
#pragma unroll
  for (int ni = 0; ni < 4; ++ni) {
    int col = wc * 64 + ni * 16 + lr;
    bcol[ni] = bias[col]; gcol[ni] = gamma[col]; zcol[ni] = beta[col];
  }
#pragma unroll
  for (int mi = 0; mi < 4; ++mi) {
#pragma unroll
    for (int j = 0; j < 4; ++j) {
      float s = 0.f, ss = 0.f;
#pragma unroll
      for (int ni = 0; ni < 4; ++ni) {
        float v = acc2[mi][ni][j] + bcol[ni];
        acc2[mi][ni][j] = v;
        s += v; ss += v * v;
      }
#pragma unroll
      for (int m = 1; m < 16; m <<= 1) { s += __shfl_xor(s, m); ss += __shfl_xor(ss, m); }
      if (lr == 0) {
        int rl = wr * 64 + mi * 16 + q * 4 + j;
        redp[(0 * 128 + rl) * 4 + wc] = s;
        redp[(1 * 128 + rl) * 4 + wc] = ss;
      }
    }
  }
  __syncthreads();
#pragma unroll
  for (int mi = 0; mi < 4; ++mi) {
#pragma unroll
    for (int j = 0; j < 4; ++j) {
      int rl = wr * 64 + mi * 16 + q * 4 + j;
      float s = redp[(0 * 128 + rl) * 4 + 0] + redp[(0 * 128 + rl) * 4 + 1] +
                redp[(0 * 128 + rl) * 4 + 2] + redp[(0 * 128 + rl) * 4 + 3];
      float ss = redp[(1 * 128 + rl) * 4 + 0] + redp[(1 * 128 + rl) * 4 + 1] +
                 redp[(1 * 128 + rl) * 4 + 2] + redp[(1 * 128 + rl) * 4 + 3];
      float mean = s * (1.f / 256.f);
      float var = ss * (1.f / 256.f) - mean * mean;
      float inv = rsqrtf(var + 1e-5f);
#pragma unroll
      for (int ni = 0; ni < 4; ++ni) {
        float v = (acc2[mi][ni][j] - mean) * inv * gcol[ni] + zcol[ni];
        acc2[mi][ni][j] = v > 0.f ? v : 0.f;
      }
    }
  }
#pragma unroll
  for (int ni = 0; ni < 4; ++ni) {
    float cs = 0.f;
#pragma unroll
    for (int mi = 0; mi < 4; ++mi) {
#pragma unroll
      for (int j = 0; j < 4; ++j) cs += acc2[mi][ni][j];
    }
    cs += __shfl_xor(cs, 16);
    cs += __shfl_xor(cs, 32);
    if (q == 0) {
      int col = wc * 64 + ni * 16 + lr;
      gpart[(((size_t)b * NMB + mb) * 2 + wr) * 256 + col] = cs;
    }
  }
}

__global__ void k_readout(const float* __restrict__ gpart, const float* __restrict__ Wa,
                          const float* __restrict__ ba, const float* __restrict__ Wl,
                          const float* __restrict__ bl, float* __restrict__ out) {
  __shared__ float gl[256];
  int b = blockIdx.x, t = threadIdx.x;  // 256 threads
  float s = 0.f;
#pragma unroll 4
  for (int p = 0; p < 32; ++p) s += gpart[((size_t)b * 32 + p) * 256 + t];
  gl[t] = s * (1.f / 2048.f);
  __syncthreads();
  if (t < 128) {
    int k = t & 63;
    const float* W = (t >= 64) ? Wl : Wa;
    const float* bb = (t >= 64) ? bl : ba;
    float a = 0.f;
    for (int h = 0; h < 256; ++h) a += gl[h] * W[h * 64 + k];
    a += bb[k];
    out[((t >= 64) ? 2048 : 0) + b * 64 + k] = a;
  }
}

extern "C" void kernel_launch(void* const* d_in, const int* in_sizes, int n_in,
                              void* d_out, int out_size, void* d_ws, size_t ws_size,
                              hipStream_t stream) {
  const float* A_hat = (const float*)d_in[0];
  const float* X   = (const float*)d_in[1];
  const float* W1  = (const float*)d_in[2];
  const float* b1  = (const float*)d_in[3];
  const float* g1  = (const float*)d_in[4];
  const float* be1 = (const float*)d_in[5];
  const float* W2  = (const float*)d_in[6];
  const float* b2  = (const float*)d_in[7];
  const float* g2  = (const float*)d_in[8];
  const float* be2 = (const float*)d_in[9];
  const float* Wa  = (const float*)d_in[10];
  const float* ba  = (const float*)d_in[11];
  const float* Wl  = (const float*)d_in[12];
  const float* bl  = (const float*)d_in[13];

  char* ws = (char*)d_ws;
  const size_t MB = 1024 * 1024;
  unsigned short* XT  = (unsigned short*)(ws);                         // 16 MiB (B,128,2048)
  unsigned short* H1T = (unsigned short*)(ws + 16 * MB);               // 32 MiB (B,256,2048)
  unsigned short* W1T = (unsigned short*)(ws + 48 * MB);               // 64 KB (256x128)
  unsigned short* W2T = (unsigned short*)(ws + 48 * MB + 256 * 1024);  // 128 KB (256x256)
  float* gpart        = (float*)(ws + 49 * MB);                        // 1 MiB (B,32,256)

  // prep: transposed bf16 copies (X + W1 + W2 in one launch)
  k_tr_all<<<dim3(8288), 256, 0, stream>>>(X, XT, W1, W1T, W2, W2T);
  // layer 1 fused (R7-proven): H1T = relu(LN(A@X @ W1 + b1))^T
  k_agg_fused<128, 0><<<dim3(16, 1, 32), 512, 0, stream>>>(
      A_hat, XT, W1T, b1, g1, be1, H1T, nullptr);
  // layer 2 fused: A in registers, B-only LDS, 80 KB -> 2 blocks/CU
  k_agg2<<<dim3(16, 1, 32), 512, 0, stream>>>(
      A_hat, H1T, W2T, b2, g2, be2, gpart);
  // readout
  k_readout<<<dim3(32), 256, 0, stream>>>(gpart, Wa, ba, Wl, bl, (float*)d_out);
}